// Round 16
// baseline (284.942 us; speedup 1.0000x reference)
//
#include <hip/hip_runtime.h>

// stackCLSTM: T=32, B=128, I=64, H=128, E=4, N_TRAP=100
// ws layout (float-word offsets):
//   W_all  [64][3072] fp32        @ 0         (196608)
//   bias   [3072] fp32            @ 196608    (3072)
//   WhhH   [e][kq][i4][lane][q]   @ 199680    (131072)  fp16-pair packed Whh h-part (uint4 rows)
//   WgH    [e][kq][16][5][128] u32@ 330752    (163840)  fp16-pair packed gate h-part
//   XG     [4096][3072] fp32      @ 494592    (12582912)
//   Gst    [4][4096*512] fp32     @ 13077504  (8388608)  handoff to k3 twins (IC atomics)
//   hbuf   [2][64][4 copy][256 pair][2 slot] u32 @ 21466112 (262144)
//   pflag  [64][4] int            @ 21728256  (256)      per-(grp,e) step progress
#define OFF_WALL   0
#define OFF_BIAS   196608
#define OFF_WHHH   199680
#define OFF_WGH    330752
#define OFF_XG     494592
#define OFF_GST    13077504
#define OFF_HBUF   21466112
#define OFF_PFLAG  21728256
#define GST_PLANE  2097152

typedef _Float16 half2_t __attribute__((ext_vector_type(2)));

__device__ __forceinline__ float fast_sig(float x) {
    return __fdividef(1.f, 1.f + __expf(-x));
}
__device__ __forceinline__ float sig_e(float y) {   // 1/(e^y + 1), native exp+rcp
    return __builtin_amdgcn_rcpf(__expf(y) + 1.f);
}
__device__ __forceinline__ unsigned pack2h(float a, float b) {
    _Float16 ha = (_Float16)a, hb = (_Float16)b;
    unsigned short ua = __builtin_bit_cast(unsigned short, ha);
    unsigned short ub = __builtin_bit_cast(unsigned short, hb);
    return ((unsigned)ub << 16) | ua;
}
__device__ __forceinline__ float dot2(unsigned w, unsigned h, float acc) {
    return __builtin_amdgcn_fdot2(__builtin_bit_cast(half2_t, w),
                                  __builtin_bit_cast(half2_t, h), acc, false);
}

// ---------------- K0: pack weights + sentinel hbuf + zero pflag ----------------
__global__ __launch_bounds__(256) void k0_pack(
    const float* __restrict__ Wh_w, const float* __restrict__ Wh_b,
    const float* __restrict__ Wi_w, const float* __restrict__ Wi_b,
    const float* __restrict__ Wf_w, const float* __restrict__ Wf_b,
    const float* __restrict__ Wd_w, const float* __restrict__ Wd_b,
    const float* __restrict__ Wg_w, const float* __restrict__ Wg_b,
    const float* __restrict__ Wo_w, const float* __restrict__ Wo_b,
    float* __restrict__ ws)
{
    const float* gw[5] = {Wi_w, Wf_w, Wd_w, Wg_w, Wo_w};
    const float* gb[5] = {Wi_b, Wf_b, Wd_b, Wg_b, Wo_b};
    int idx = blockIdx.x * 256 + threadIdx.x;
    if (idx < 196608) {            // W_all [r<64][col<3072]
        int r = idx / 3072, col = idx - r * 3072;
        float v;
        if (col < 512) {
            v = Wh_w[r * 512 + col] + Wh_w[(192 + r) * 512 + col]
              + Wh_w[(384 + r) * 512 + col] + Wh_w[(576 + r) * 512 + col];
        } else {
            int q = col - 512;
            int e = q / 640;
            int rem = q - e * 640;
            int g = rem >> 7, h = rem & 127;
            v = gw[g][(e * 192 + r) * 128 + h];
        }
        ws[OFF_WALL + idx] = v;
    } else if (idx < 327680) {     // WhhH [e][kq][i4][lane][q]
        int i = idx - 196608;
        int q    = i & 3;
        int lane = (i >> 2) & 127;
        int i4   = (i >> 9) & 15;
        int kq   = (i >> 13) & 3;
        int e    = i >> 15;
        int kp = i4 * 4 + q;
        int k0 = kq * 128 + 2 * kp;
        int r0 = (k0 >> 7) * 192 + 64 + (k0 & 127);
        float w0 = Wh_w[r0 * 512 + e * 128 + lane];
        float w1 = Wh_w[(r0 + 1) * 512 + e * 128 + lane];
        reinterpret_cast<unsigned*>(ws + OFF_WHHH)[i] = pack2h(w0, w1);
    } else if (idx < 491520) {     // WgH [e][kq][16 ii][5 g][128 lane]
        int i = idx - 327680;
        int lane = i & 127;
        int gg = (i >> 7) % 5;
        int rest = (i >> 7) / 5;
        int ii = rest & 15;
        int kq = (rest >> 4) & 3;
        int e  = rest >> 6;
        int k0 = kq * 32 + 2 * ii, k1 = k0 + 1;
        float w0 = gw[gg][(e * 192 + 64 + k0) * 128 + lane];
        float w1 = gw[gg][(e * 192 + 64 + k1) * 128 + lane];
        reinterpret_cast<unsigned*>(ws + OFF_WGH)[i] = pack2h(w0, w1);
    }
    if (idx < 3072) {              // bias
        float v;
        if (idx < 512) v = Wh_b[idx];
        else {
            int q = idx - 512;
            int e = q / 640;
            int rem = q - e * 640;
            int g = rem >> 7, h = rem & 127;
            v = gb[g][e * 128 + h];
        }
        ws[OFF_BIAS + idx] = v;
    }
    if (idx < 262144) {            // sentinel-fill hbuf every launch (graph-replay safe)
        reinterpret_cast<unsigned*>(ws + OFF_HBUF)[idx] = 0xFFFFFFFFu;
    }
    if (idx < 256) {               // zero progress flags every launch
        reinterpret_cast<int*>(ws + OFF_PFLAG)[idx] = 0;
    }
}

// ---------------- K1: XG[4096][3072] = X[4096][64] @ W_all + bias ----------------
__global__ __launch_bounds__(256) void k1_xproj(
    const float* __restrict__ x, const float* wsr, float* XG)
{
    __shared__ __align__(16) float XT[64 * 68];
    const float* W_all = wsr + OFF_WALL;
    const float* bias  = wsr + OFF_BIAS;
    int bid = blockIdx.x;
    int ct = bid % 48, rt = bid / 48;
    int r0 = rt * 64, c0 = ct * 64;
    for (int p = threadIdx.x; p < 4096; p += 256) {
        int i = p >> 6, k = p & 63;
        XT[k * 68 + i] = x[(r0 + i) * 64 + k];
    }
    __syncthreads();
    int col = c0 + (threadIdx.x & 63);
    int iq = threadIdx.x >> 6;
    float acc[16];
    #pragma unroll
    for (int r = 0; r < 16; r++) acc[r] = 0.f;
    const float* wp = W_all + col;
    #pragma unroll 4
    for (int k = 0; k < 64; k++) {
        float w = wp[k * 3072];
        const float4* xt4 = reinterpret_cast<const float4*>(&XT[k * 68 + iq * 16]);
        #pragma unroll
        for (int r4 = 0; r4 < 4; r4++) {
            float4 xv = xt4[r4];
            acc[r4 * 4 + 0] = fmaf(xv.x, w, acc[r4 * 4 + 0]);
            acc[r4 * 4 + 1] = fmaf(xv.y, w, acc[r4 * 4 + 1]);
            acc[r4 * 4 + 2] = fmaf(xv.z, w, acc[r4 * 4 + 2]);
            acc[r4 * 4 + 3] = fmaf(xv.w, w, acc[r4 * 4 + 3]);
        }
    }
    float bv = bias[col];
    #pragma unroll
    for (int r = 0; r < 16; r++) {
        int row = r0 + iq * 16 + r;
        XG[row * 3072 + col] = acc[r] + bv;
    }
}

// ---------------- K2: 512 blocks. 0..255 = recurrence (R13 structure, Whh streamed
// from L2 so LDS is small). 256..511 = co-resident k3 twins consuming Gst per step.
// One-way producer->consumer: k2 never waits on k3 (deadlock-free under any placement).
__global__ __launch_bounds__(512, 2) void k2_recur(
    const uint4* __restrict__ WhhH4,
    const unsigned* __restrict__ WgH,
    const float* __restrict__ XG,
    const float* __restrict__ dt_time,
    const float* __restrict__ alpha,
    float* __restrict__ Gst,
    unsigned* __restrict__ hbuf,
    int* __restrict__ pflag,
    float* __restrict__ lam_out,
    float* __restrict__ integ_out)
{
    __shared__ __align__(16) unsigned hsP[2][64];
    __shared__ __align__(16) unsigned hOut[128];
    __shared__ float pA[4][2][128];
    __shared__ float pB[4][2][5][128];
    __shared__ float red[4];
    __shared__ float redI[8];
    const int tid = threadIdx.x;
    const int bid = blockIdx.x;

    if (bid >= 256) {
        // ================= k3 twin: trapezoid consumer =================
        const int tb = bid - 256;
        const int e3 = (tb >> 3) & 3;
        const int g3 = (tb & 7) | ((tb >> 5) << 3);
        const int b03 = g3 * 2;
        const int half = tid >> 8;
        const int s3 = (tid >> 7) & 1;
        const int l3 = tid & 127;
        const float av3 = alpha[e3 * 128 + l3];
        int* pf = pflag + g3 * 4 + e3;
        for (int t = 0; t < 32; ++t) {
            if (tid == 0) {
                while (__hip_atomic_load(pf, __ATOMIC_RELAXED,
                                         __HIP_MEMORY_SCOPE_AGENT) <= t)
                    __builtin_amdgcn_s_sleep(2);
            }
            __syncthreads();
            asm volatile("" ::: "memory");
            const int row = t * 128 + b03 + s3;
            const size_t go = (size_t)row * 512 + e3 * 128 + l3;
            float gc = __hip_atomic_load(&Gst[0 * GST_PLANE + go], __ATOMIC_RELAXED, __HIP_MEMORY_SCOPE_AGENT);
            float df = __hip_atomic_load(&Gst[1 * GST_PLANE + go], __ATOMIC_RELAXED, __HIP_MEMORY_SCOPE_AGENT);
            float dl = __hip_atomic_load(&Gst[2 * GST_PLANE + go], __ATOMIC_RELAXED, __HIP_MEMORY_SCOPE_AGENT);
            float og = __hip_atomic_load(&Gst[3 * GST_PLANE + go], __ATOMIC_RELAXED, __HIP_MEMORY_SCOPE_AGENT);
            float dtv = dt_time[row];
            float g2 = 2.f * gc, d2 = 2.f * df;
            float q  = dl * dtv;
            float r  = __expf(-0.01f * q);
            float r2 = r * r, r4 = r2 * r2;
            float T;
            if (half == 0) {
                float E1 = r, E2 = r2, E3 = r2 * r, E4 = r4;
                float s1 = 0.f, s2 = 0.f, s3c = 0.f, s4 = 0.f;
                #pragma unroll
                for (int k = 0; k < 12; ++k) {      // k = 1..48
                    s1 += sig_e(fmaf(d2, E1, g2)); E1 *= r4;
                    s2 += sig_e(fmaf(d2, E2, g2)); E2 *= r4;
                    s3c += sig_e(fmaf(d2, E3, g2)); E3 *= r4;
                    s4 += sig_e(fmaf(d2, E4, g2)); E4 *= r4;
                }
                T = 48.5f - 2.f * ((s1 + s2) + (s3c + s4)) - sig_e(g2 + d2);
            } else {
                float E49 = __expf(-0.49f * q);
                float E1 = E49, E2 = E49 * r, E3 = E49 * r2, E4 = E49 * r2 * r;
                float s1 = 0.f, s2 = 0.f, s3c = 0.f, s4 = 0.f;
                #pragma unroll
                for (int k = 0; k < 13; ++k) {      // k = 49..100
                    s1 += sig_e(fmaf(d2, E1, g2)); E1 *= r4;
                    s2 += sig_e(fmaf(d2, E2, g2)); E2 *= r4;
                    s3c += sig_e(fmaf(d2, E3, g2)); E3 *= r4;
                    s4 += sig_e(fmaf(d2, E4, g2)); E4 *= r4;
                }
                float e100 = __expf(-q);
                T = 51.5f - 2.f * ((s1 + s2) + (s3c + s4)) + sig_e(fmaf(d2, e100, g2));
            }
            float v = av3 * og * T;
            #pragma unroll
            for (int off = 32; off > 0; off >>= 1) v += __shfl_down(v, off, 64);
            if ((tid & 63) == 0) redI[tid >> 6] = v;
            __syncthreads();
            // waves for slot s: {2s, 2s+1, 4+2s, 5+2s}
            if (tid < 2) {
                int row2 = t * 128 + b03 + tid;
                float dtv2 = dt_time[row2];
                float vv = (tid == 0) ? (redI[0] + redI[1] + redI[4] + redI[5])
                                      : (redI[2] + redI[3] + redI[6] + redI[7]);
                integ_out[row2 * 4 + e3] = vv * (dtv2 * 0.01f);
            }
        }
        return;
    }

    // ================= k2 producer: recurrence =================
    const int e   = (bid >> 3) & 3;
    const int grp = (bid & 7) | ((bid >> 5) << 3);
    const int b0  = grp * 2;
    const int kq  = tid >> 7;
    const int lane = tid & 127;
    const int l64 = tid & 63;
    const int s = (tid >> 7) & 1, l = lane;
    const uint4* wap = WhhH4 + (size_t)e * 8192 + (size_t)(kq * 16) * 128 + lane;
    unsigned wg[5][16];
    #pragma unroll
    for (int i = 0; i < 16; i++) {
        #pragma unroll
        for (int g = 0; g < 5; g++)
            wg[g][i] = WgH[(((e * 4 + kq) * 16 + i) * 5 + g) * 128 + lane];
    }
    const float av = alpha[e * 128 + lane];
    int* pf2 = pflag + grp * 4 + e;
    float cst = 0.f;
    __syncthreads();

    for (int t = 0; t < 32; ++t) {
        const int row0 = t * 128 + b0;
        // (1) XG prefetch
        float xg0 = 0.f, xgg0 = 0.f, xgg1 = 0.f, xgg2 = 0.f, xgg3 = 0.f, xgg4 = 0.f;
        if (tid < 256) {
            const float* base = XG + (size_t)(row0 + s) * 3072;
            xg0 = base[e * 128 + l];
            const float* gp = base + 512 + e * 640 + l;
            xgg0 = gp[0]; xgg1 = gp[128]; xgg2 = gp[256]; xgg3 = gp[384]; xgg4 = gp[512];
        }
        if (t > 0) {
            // (2) acquire the single uint2 this thread broadcasts from (data-as-flag)
            uint2 hu;
            if (kq == e) {
                hu.x = hOut[l64];
                hu.y = hOut[64 + l64];
            } else {
                const unsigned long long* ap =
                    reinterpret_cast<const unsigned long long*>(
                        hbuf + ((size_t)((t & 1) * 64 + grp) * 4 + e) * 512)
                    + (kq * 64 + l64);
                unsigned long long v = __hip_atomic_load(ap, __ATOMIC_RELAXED,
                                                         __HIP_MEMORY_SCOPE_AGENT);
                while (v == ~0ull) {
                    __builtin_amdgcn_s_sleep(1);
                    v = __hip_atomic_load(ap, __ATOMIC_RELAXED,
                                          __HIP_MEMORY_SCOPE_AGENT);
                }
                hu.x = (unsigned)v;
                hu.y = (unsigned)(v >> 32);
            }
            // (3) phase A: Whh streamed from L2, readlane broadcast dots
            float a0 = 0.f, a1 = 0.f;
            #pragma unroll
            for (int i4 = 0; i4 < 16; ++i4) {
                uint4 w = wap[i4 * 128];
                unsigned h0, h1;
                h0 = __builtin_amdgcn_readlane(hu.x, i4 * 4 + 0);
                h1 = __builtin_amdgcn_readlane(hu.y, i4 * 4 + 0);
                a0 = dot2(w.x, h0, a0); a1 = dot2(w.x, h1, a1);
                h0 = __builtin_amdgcn_readlane(hu.x, i4 * 4 + 1);
                h1 = __builtin_amdgcn_readlane(hu.y, i4 * 4 + 1);
                a0 = dot2(w.y, h0, a0); a1 = dot2(w.y, h1, a1);
                h0 = __builtin_amdgcn_readlane(hu.x, i4 * 4 + 2);
                h1 = __builtin_amdgcn_readlane(hu.y, i4 * 4 + 2);
                a0 = dot2(w.z, h0, a0); a1 = dot2(w.z, h1, a1);
                h0 = __builtin_amdgcn_readlane(hu.x, i4 * 4 + 3);
                h1 = __builtin_amdgcn_readlane(hu.y, i4 * 4 + 3);
                a0 = dot2(w.w, h0, a0); a1 = dot2(w.w, h1, a1);
            }
            pA[kq][0][lane] = a0;
            pA[kq][1][lane] = a1;
        }
        __syncthreads();   // bar1: pA ready; both pollers of each word have read
        if (t > 0 && kq != e && lane < 64) {   // re-arm polled words
            unsigned long long* ap =
                reinterpret_cast<unsigned long long*>(
                    hbuf + ((size_t)((t & 1) * 64 + grp) * 4 + e) * 512)
                + (kq * 64 + l64);
            __hip_atomic_store(ap, ~0ull, __ATOMIC_RELAXED, __HIP_MEMORY_SCOPE_AGENT);
        }
        if (tid < 256) {
            float hs = xg0;
            if (t > 0) hs += pA[0][s][l] + pA[1][s][l] + pA[2][s][l] + pA[3][s][l];
            float hi = __shfl_down(hs, 1, 64);
            if ((l & 1) == 0) hsP[s][l >> 1] = pack2h(hs, hi);
        }
        __syncthreads();   // bar2: hsP ready
        // (5) phase B: readlane broadcast gate dots
        float b0a = 0.f, b1a = 0.f, b2a = 0.f, b3a = 0.f, b4a = 0.f;
        float b0b = 0.f, b1b = 0.f, b2b = 0.f, b3b = 0.f, b4b = 0.f;
        {
            unsigned hv = hsP[(l64 >> 4) & 1][kq * 16 + (l64 & 15)];
            #pragma unroll
            for (int i = 0; i < 16; ++i) {
                unsigned h0 = __builtin_amdgcn_readlane(hv, i);
                unsigned h1 = __builtin_amdgcn_readlane(hv, 16 + i);
                b0a = dot2(wg[0][i], h0, b0a); b0b = dot2(wg[0][i], h1, b0b);
                b1a = dot2(wg[1][i], h0, b1a); b1b = dot2(wg[1][i], h1, b1b);
                b2a = dot2(wg[2][i], h0, b2a); b2b = dot2(wg[2][i], h1, b2b);
                b3a = dot2(wg[3][i], h0, b3a); b3b = dot2(wg[3][i], h1, b3b);
                b4a = dot2(wg[4][i], h0, b4a); b4b = dot2(wg[4][i], h1, b4b);
            }
        }
        pB[kq][0][0][lane] = b0a; pB[kq][0][1][lane] = b1a; pB[kq][0][2][lane] = b2a;
        pB[kq][0][3][lane] = b3a; pB[kq][0][4][lane] = b4a;
        pB[kq][1][0][lane] = b0b; pB[kq][1][1][lane] = b1b; pB[kq][1][2][lane] = b2b;
        pB[kq][1][3][lane] = b3b; pB[kq][1][4][lane] = b4b;
        __syncthreads();   // bar3: pB ready
        // (6) cell update (tid<256); Gst handoff via agent-scope stores
        if (tid < 256) {
            float ai = pB[0][s][0][l] + pB[1][s][0][l] + pB[2][s][0][l] + pB[3][s][0][l] + xgg0;
            float af = pB[0][s][1][l] + pB[1][s][1][l] + pB[2][s][1][l] + pB[3][s][1][l] + xgg1;
            float ad = pB[0][s][2][l] + pB[1][s][2][l] + pB[2][s][2][l] + pB[3][s][2][l] + xgg2;
            float ag = pB[0][s][3][l] + pB[1][s][3][l] + pB[2][s][3][l] + pB[3][s][3][l] + xgg3;
            float ao = pB[0][s][4][l] + pB[1][s][4][l] + pB[2][s][4][l] + pB[3][s][4][l] + xgg4;
            float ig = fast_sig(ai);
            float fg = fast_sig(af);
            float dl = __expf(ad);
            float gt = tanhf(ag);
            float og = fast_sig(ao);
            float gc = fmaf(fg, cst, ig * gt);
            float df = cst - gc;
            float dtv = dt_time[row0 + s];
            cst = fmaf(df, __expf(-dl * dtv), gc);
            float hn = og * tanhf(cst);
            size_t go = (size_t)(row0 + s) * 512 + e * 128 + l;
            __hip_atomic_store(&Gst[0 * GST_PLANE + go], gc, __ATOMIC_RELAXED, __HIP_MEMORY_SCOPE_AGENT);
            __hip_atomic_store(&Gst[1 * GST_PLANE + go], df, __ATOMIC_RELAXED, __HIP_MEMORY_SCOPE_AGENT);
            __hip_atomic_store(&Gst[2 * GST_PLANE + go], dl, __ATOMIC_RELAXED, __HIP_MEMORY_SCOPE_AGENT);
            __hip_atomic_store(&Gst[3 * GST_PLANE + go], og, __ATOMIC_RELAXED, __HIP_MEMORY_SCOPE_AGENT);
            float hi = __shfl_down(hn, 1, 64);
            if ((l & 1) == 0) hOut[s * 64 + (l >> 1)] = pack2h(hn, hi);
            float lm = av * hn;
            #pragma unroll
            for (int off = 32; off > 0; off >>= 1) lm += __shfl_down(lm, off, 64);
            if ((tid & 63) == 0) red[tid >> 6] = lm;
        }
        __syncthreads();   // bar4: hOut/red ready; vmcnt drained (Gst at IC)
        if (tid == 0) {
            lam_out[(row0 + 0) * 4 + e] = red[0] + red[1];
            lam_out[(row0 + 1) * 4 + e] = red[2] + red[3];
            __hip_atomic_store(pf2, t + 1, __ATOMIC_RELAXED,
                               __HIP_MEMORY_SCOPE_AGENT);   // release step t to twin
        }
        // (7) publish h: one 64-bit word per pair to each of 3 consumer copies
        if (tid < 192) {
            int cpy = tid >> 6;
            cpy += (cpy >= e) ? 1 : 0;
            int qp = tid & 63;
            unsigned long long v =
                ((unsigned long long)hOut[64 + qp] << 32) | (unsigned long long)hOut[qp];
            unsigned long long* dst =
                reinterpret_cast<unsigned long long*>(
                    hbuf + ((size_t)(((t + 1) & 1) * 64 + grp) * 4 + cpy) * 512)
                + (e * 64 + qp);
            __hip_atomic_store(dst, v, __ATOMIC_RELAXED, __HIP_MEMORY_SCOPE_AGENT);
        }
    }
}

extern "C" void kernel_launch(void* const* d_in, const int* in_sizes, int n_in,
                              void* d_out, int out_size, void* d_ws, size_t ws_size,
                              hipStream_t stream)
{
    const float* x_time  = (const float*)d_in[0];
    const float* dt_time = (const float*)d_in[1];
    const float* Wh_w = (const float*)d_in[2];
    const float* Wh_b = (const float*)d_in[3];
    const float* Wi_w = (const float*)d_in[4];
    const float* Wi_b = (const float*)d_in[5];
    const float* Wf_w = (const float*)d_in[6];
    const float* Wf_b = (const float*)d_in[7];
    const float* Wd_w = (const float*)d_in[8];
    const float* Wd_b = (const float*)d_in[9];
    const float* Wg_w = (const float*)d_in[10];
    const float* Wg_b = (const float*)d_in[11];
    const float* Wo_w = (const float*)d_in[12];
    const float* Wo_b = (const float*)d_in[13];
    const float* alpha = (const float*)d_in[14];

    float* ws = (float*)d_ws;
    float* XG   = ws + OFF_XG;
    float* Gst  = ws + OFF_GST;
    unsigned* hbuf = (unsigned*)(ws + OFF_HBUF);
    int* pflag = (int*)(ws + OFF_PFLAG);
    float* lam_out   = (float*)d_out;
    float* integ_out = lam_out + 32 * 128 * 4;

    k0_pack<<<3072, 256, 0, stream>>>(Wh_w, Wh_b, Wi_w, Wi_b, Wf_w, Wf_b,
                                      Wd_w, Wd_b, Wg_w, Wg_b, Wo_w, Wo_b, ws);
    k1_xproj<<<3072, 256, 0, stream>>>(x_time, ws, XG);
    k2_recur<<<512, 512, 0, stream>>>(
        (const uint4*)(ws + OFF_WHHH), (const unsigned*)(ws + OFF_WGH),
        XG, dt_time, alpha, Gst, hbuf, pflag, lam_out, integ_out);
}

// Round 17
// 204.956 us; speedup vs baseline: 1.3903x; 1.3903x over previous
//
#include <hip/hip_runtime.h>

// stackCLSTM: T=32, B=128, I=64, H=128, E=4, N_TRAP=100
// ws layout (float-word offsets):
//   W_all  [64][3072] fp32        @ 0         (196608)
//   bias   [3072] fp32            @ 196608    (3072)
//   WhhH   [e][kq][i4][lane][q]   @ 199680    (131072)  fp16-pair packed Whh h-part (uint4 rows)
//   WgH    [e][kq][16][5][128] u32@ 330752    (163840)  fp16-pair packed gate h-part
//   XG     [4096][3072] fp32      @ 494592    (12582912)
//   Gst    [4096*512] float4      @ 13077504  (8388608)  {2g,2d,dl*dt,av*og} per tuple
//   hbuf   [2][64][4 copy][256 pair][2 slot] u32 @ 21466112 (262144)
//          data-as-flag h exchange; sentinel 0xFFFFFFFF per u32 half
#define OFF_WALL   0
#define OFF_BIAS   196608
#define OFF_WHHH   199680
#define OFF_WGH    330752
#define OFF_XG     494592
#define OFF_GST    13077504
#define OFF_HBUF   21466112

typedef _Float16 half2_t __attribute__((ext_vector_type(2)));

__device__ __forceinline__ float fast_sig(float x) {
    return __fdividef(1.f, 1.f + __expf(-x));
}
__device__ __forceinline__ float sig_e(float y) {   // 1/(e^y + 1), native exp+rcp
    return __builtin_amdgcn_rcpf(__expf(y) + 1.f);
}
__device__ __forceinline__ unsigned pack2h(float a, float b) {
    _Float16 ha = (_Float16)a, hb = (_Float16)b;
    unsigned short ua = __builtin_bit_cast(unsigned short, ha);
    unsigned short ub = __builtin_bit_cast(unsigned short, hb);
    return ((unsigned)ub << 16) | ua;
}
__device__ __forceinline__ float dot2(unsigned w, unsigned h, float acc) {
    return __builtin_amdgcn_fdot2(__builtin_bit_cast(half2_t, w),
                                  __builtin_bit_cast(half2_t, h), acc, false);
}

// ---------------- K0: pack weights + sentinel-fill hbuf ----------------
__global__ __launch_bounds__(256) void k0_pack(
    const float* __restrict__ Wh_w, const float* __restrict__ Wh_b,
    const float* __restrict__ Wi_w, const float* __restrict__ Wi_b,
    const float* __restrict__ Wf_w, const float* __restrict__ Wf_b,
    const float* __restrict__ Wd_w, const float* __restrict__ Wd_b,
    const float* __restrict__ Wg_w, const float* __restrict__ Wg_b,
    const float* __restrict__ Wo_w, const float* __restrict__ Wo_b,
    float* __restrict__ ws)
{
    const float* gw[5] = {Wi_w, Wf_w, Wd_w, Wg_w, Wo_w};
    const float* gb[5] = {Wi_b, Wf_b, Wd_b, Wg_b, Wo_b};
    int idx = blockIdx.x * 256 + threadIdx.x;
    if (idx < 196608) {            // W_all [r<64][col<3072]
        int r = idx / 3072, col = idx - r * 3072;
        float v;
        if (col < 512) {
            v = Wh_w[r * 512 + col] + Wh_w[(192 + r) * 512 + col]
              + Wh_w[(384 + r) * 512 + col] + Wh_w[(576 + r) * 512 + col];
        } else {
            int q = col - 512;
            int e = q / 640;
            int rem = q - e * 640;
            int g = rem >> 7, h = rem & 127;
            v = gw[g][(e * 192 + r) * 128 + h];
        }
        ws[OFF_WALL + idx] = v;
    } else if (idx < 327680) {     // WhhH [e][kq][i4][lane][q]  (uint4-per-lane rows)
        int i = idx - 196608;
        int q    = i & 3;
        int lane = (i >> 2) & 127;
        int i4   = (i >> 9) & 15;
        int kq   = (i >> 13) & 3;
        int e    = i >> 15;
        int kp = i4 * 4 + q;
        int k0 = kq * 128 + 2 * kp;
        int r0 = (k0 >> 7) * 192 + 64 + (k0 & 127);
        float w0 = Wh_w[r0 * 512 + e * 128 + lane];
        float w1 = Wh_w[(r0 + 1) * 512 + e * 128 + lane];
        reinterpret_cast<unsigned*>(ws + OFF_WHHH)[i] = pack2h(w0, w1);
    } else if (idx < 491520) {     // WgH [e][kq][16 ii][5 g][128 lane]
        int i = idx - 327680;
        int lane = i & 127;
        int gg = (i >> 7) % 5;
        int rest = (i >> 7) / 5;
        int ii = rest & 15;
        int kq = (rest >> 4) & 3;
        int e  = rest >> 6;
        int k0 = kq * 32 + 2 * ii, k1 = k0 + 1;
        float w0 = gw[gg][(e * 192 + 64 + k0) * 128 + lane];
        float w1 = gw[gg][(e * 192 + 64 + k1) * 128 + lane];
        reinterpret_cast<unsigned*>(ws + OFF_WGH)[i] = pack2h(w0, w1);
    }
    if (idx < 3072) {              // bias
        float v;
        if (idx < 512) v = Wh_b[idx];
        else {
            int q = idx - 512;
            int e = q / 640;
            int rem = q - e * 640;
            int g = rem >> 7, h = rem & 127;
            v = gb[g][e * 128 + h];
        }
        ws[OFF_BIAS + idx] = v;
    }
    if (idx < 262144) {            // sentinel-fill hbuf every launch (graph-replay safe)
        reinterpret_cast<unsigned*>(ws + OFF_HBUF)[idx] = 0xFFFFFFFFu;
    }
}

// ---------------- K1: XG[4096][3072] = X[4096][64] @ W_all + bias ----------------
__global__ __launch_bounds__(256) void k1_xproj(
    const float* __restrict__ x, const float* wsr, float* XG)
{
    __shared__ __align__(16) float XT[64 * 68];
    const float* W_all = wsr + OFF_WALL;
    const float* bias  = wsr + OFF_BIAS;
    int bid = blockIdx.x;
    int ct = bid % 48, rt = bid / 48;
    int r0 = rt * 64, c0 = ct * 64;
    for (int p = threadIdx.x; p < 4096; p += 256) {
        int i = p >> 6, k = p & 63;
        XT[k * 68 + i] = x[(r0 + i) * 64 + k];
    }
    __syncthreads();
    int col = c0 + (threadIdx.x & 63);
    int iq = threadIdx.x >> 6;
    float acc[16];
    #pragma unroll
    for (int r = 0; r < 16; r++) acc[r] = 0.f;
    const float* wp = W_all + col;
    #pragma unroll 4
    for (int k = 0; k < 64; k++) {
        float w = wp[k * 3072];
        const float4* xt4 = reinterpret_cast<const float4*>(&XT[k * 68 + iq * 16]);
        #pragma unroll
        for (int r4 = 0; r4 < 4; r4++) {
            float4 xv = xt4[r4];
            acc[r4 * 4 + 0] = fmaf(xv.x, w, acc[r4 * 4 + 0]);
            acc[r4 * 4 + 1] = fmaf(xv.y, w, acc[r4 * 4 + 1]);
            acc[r4 * 4 + 2] = fmaf(xv.z, w, acc[r4 * 4 + 2]);
            acc[r4 * 4 + 3] = fmaf(xv.w, w, acc[r4 * 4 + 3]);
        }
    }
    float bv = bias[col];
    #pragma unroll
    for (int r = 0; r < 16; r++) {
        int row = r0 + iq * 16 + r;
        XG[row * 3072 + col] = acc[r] + bv;
    }
}

// ---------------- K2: R13 structure + early per-thread publish + float4 Gst ----
// 256 blocks x 512 threads, 1 block/CU (waL 128KB). Group of 4 (one per e) = 1 pair.
// Publish happens inside the cell-update phase (per even thread, u32 per slot) --
// one barrier earlier than R13; poll checks both u32 halves for sentinel.
// Re-arm -> publish still separated by bar2+bar3 (vmcnt-draining) => race-free.
__global__ __launch_bounds__(512, 1) void k2_recur(
    const uint4* __restrict__ WhhH4,
    const unsigned* __restrict__ WgH,
    const float* __restrict__ XG,
    const float* __restrict__ dt_time,
    const float* __restrict__ alpha,
    float4* __restrict__ Gst4,
    unsigned* __restrict__ hbuf,
    float* __restrict__ lam_out)
{
    __shared__ __align__(16) uint4 waL[8192];       // 128 KB
    __shared__ __align__(16) unsigned hsP[2][64];   // hs packed pairs [slot][pair]
    __shared__ __align__(16) unsigned hOut[128];    // this block's packed h (persists)
    __shared__ float pA[4][2][128];
    __shared__ float pB[4][2][5][128];              // [kq][s][g][l] conflict-free
    __shared__ float red[4];
    const int tid = threadIdx.x;
    const int bid = blockIdx.x;
    const int e   = (bid >> 3) & 3;
    const int grp = (bid & 7) | ((bid >> 5) << 3);
    const int b0  = grp * 2;
    const int kq  = tid >> 7;
    const int lane = tid & 127;
    const int l64 = tid & 63;
    const int s = (tid >> 7) & 1, l = lane;

    // stage Whh e-slice into LDS (once)
    {
        const uint4* src = WhhH4 + (size_t)e * 8192;
        #pragma unroll
        for (int n = 0; n < 16; ++n) waL[tid + 512 * n] = src[tid + 512 * n];
    }
    unsigned wg[5][16];
    #pragma unroll
    for (int i = 0; i < 16; i++) {
        #pragma unroll
        for (int g = 0; g < 5; g++)
            wg[g][i] = WgH[(((e * 4 + kq) * 16 + i) * 5 + g) * 128 + lane];
    }
    const float av = alpha[e * 128 + lane];
    float cst = 0.f;
    __syncthreads();   // waL ready

    for (int t = 0; t < 32; ++t) {
        const int row0 = t * 128 + b0;
        // (1) XG prefetch
        float xg0 = 0.f, xgg0 = 0.f, xgg1 = 0.f, xgg2 = 0.f, xgg3 = 0.f, xgg4 = 0.f;
        if (tid < 256) {
            const float* base = XG + (size_t)(row0 + s) * 3072;
            xg0 = base[e * 128 + l];
            const float* gp = base + 512 + e * 640 + l;
            xgg0 = gp[0]; xgg1 = gp[128]; xgg2 = gp[256]; xgg3 = gp[384]; xgg4 = gp[512];
        }
        if (t > 0) {
            // (2) acquire the single uint2 this thread broadcasts from
            uint2 hu;
            if (kq == e) {
                hu.x = hOut[l64];
                hu.y = hOut[64 + l64];
            } else {
                const unsigned long long* ap =
                    reinterpret_cast<const unsigned long long*>(
                        hbuf + ((size_t)((t & 1) * 64 + grp) * 4 + e) * 512)
                    + (kq * 64 + l64);
                unsigned long long v = __hip_atomic_load(ap, __ATOMIC_RELAXED,
                                                         __HIP_MEMORY_SCOPE_AGENT);
                while ((unsigned)v == 0xFFFFFFFFu ||
                       (unsigned)(v >> 32) == 0xFFFFFFFFu) {
                    __builtin_amdgcn_s_sleep(1);
                    v = __hip_atomic_load(ap, __ATOMIC_RELAXED,
                                          __HIP_MEMORY_SCOPE_AGENT);
                }
                hu.x = (unsigned)v;
                hu.y = (unsigned)(v >> 32);
            }
            // (3) phase A: readlane broadcast dots (VALU)
            float a0 = 0.f, a1 = 0.f;
            #pragma unroll
            for (int i4 = 0; i4 < 16; ++i4) {
                uint4 w = waL[(kq * 16 + i4) * 128 + lane];
                unsigned h0, h1;
                h0 = __builtin_amdgcn_readlane(hu.x, i4 * 4 + 0);
                h1 = __builtin_amdgcn_readlane(hu.y, i4 * 4 + 0);
                a0 = dot2(w.x, h0, a0); a1 = dot2(w.x, h1, a1);
                h0 = __builtin_amdgcn_readlane(hu.x, i4 * 4 + 1);
                h1 = __builtin_amdgcn_readlane(hu.y, i4 * 4 + 1);
                a0 = dot2(w.y, h0, a0); a1 = dot2(w.y, h1, a1);
                h0 = __builtin_amdgcn_readlane(hu.x, i4 * 4 + 2);
                h1 = __builtin_amdgcn_readlane(hu.y, i4 * 4 + 2);
                a0 = dot2(w.z, h0, a0); a1 = dot2(w.z, h1, a1);
                h0 = __builtin_amdgcn_readlane(hu.x, i4 * 4 + 3);
                h1 = __builtin_amdgcn_readlane(hu.y, i4 * 4 + 3);
                a0 = dot2(w.w, h0, a0); a1 = dot2(w.w, h1, a1);
            }
            pA[kq][0][lane] = a0;
            pA[kq][1][lane] = a1;
        }
        __syncthreads();   // bar1: pA ready; both pollers of each word have read
        // re-arm polled words (one thread per word)
        if (t > 0 && kq != e && lane < 64) {
            unsigned long long* ap =
                reinterpret_cast<unsigned long long*>(
                    hbuf + ((size_t)((t & 1) * 64 + grp) * 4 + e) * 512)
                + (kq * 64 + l64);
            __hip_atomic_store(ap, ~0ull, __ATOMIC_RELAXED, __HIP_MEMORY_SCOPE_AGENT);
        }
        if (tid < 256) {
            float hs = xg0;
            if (t > 0) hs += pA[0][s][l] + pA[1][s][l] + pA[2][s][l] + pA[3][s][l];
            float hi = __shfl_down(hs, 1, 64);
            if ((l & 1) == 0) hsP[s][l >> 1] = pack2h(hs, hi);
        }
        __syncthreads();   // bar2: hsP ready
        // (5) phase B: readlane broadcast gate dots
        float b0a = 0.f, b1a = 0.f, b2a = 0.f, b3a = 0.f, b4a = 0.f;
        float b0b = 0.f, b1b = 0.f, b2b = 0.f, b3b = 0.f, b4b = 0.f;
        {
            unsigned hv = hsP[(l64 >> 4) & 1][kq * 16 + (l64 & 15)];
            #pragma unroll
            for (int i = 0; i < 16; ++i) {
                unsigned h0 = __builtin_amdgcn_readlane(hv, i);
                unsigned h1 = __builtin_amdgcn_readlane(hv, 16 + i);
                b0a = dot2(wg[0][i], h0, b0a); b0b = dot2(wg[0][i], h1, b0b);
                b1a = dot2(wg[1][i], h0, b1a); b1b = dot2(wg[1][i], h1, b1b);
                b2a = dot2(wg[2][i], h0, b2a); b2b = dot2(wg[2][i], h1, b2b);
                b3a = dot2(wg[3][i], h0, b3a); b3b = dot2(wg[3][i], h1, b3b);
                b4a = dot2(wg[4][i], h0, b4a); b4b = dot2(wg[4][i], h1, b4b);
            }
        }
        pB[kq][0][0][lane] = b0a; pB[kq][0][1][lane] = b1a; pB[kq][0][2][lane] = b2a;
        pB[kq][0][3][lane] = b3a; pB[kq][0][4][lane] = b4a;
        pB[kq][1][0][lane] = b0b; pB[kq][1][1][lane] = b1b; pB[kq][1][2][lane] = b2b;
        pB[kq][1][3][lane] = b3b; pB[kq][1][4][lane] = b4b;
        __syncthreads();   // bar3: pB ready (>=2 vmcnt-draining barriers since re-arm)
        // (6) cell update (tid<256): float4 Gst + EARLY per-thread publish
        if (tid < 256) {
            float ai = pB[0][s][0][l] + pB[1][s][0][l] + pB[2][s][0][l] + pB[3][s][0][l] + xgg0;
            float af = pB[0][s][1][l] + pB[1][s][1][l] + pB[2][s][1][l] + pB[3][s][1][l] + xgg1;
            float ad = pB[0][s][2][l] + pB[1][s][2][l] + pB[2][s][2][l] + pB[3][s][2][l] + xgg2;
            float ag = pB[0][s][3][l] + pB[1][s][3][l] + pB[2][s][3][l] + pB[3][s][3][l] + xgg3;
            float ao = pB[0][s][4][l] + pB[1][s][4][l] + pB[2][s][4][l] + pB[3][s][4][l] + xgg4;
            float ig = fast_sig(ai);
            float fg = fast_sig(af);
            float dl = __expf(ad);
            float gt = tanhf(ag);
            float og = fast_sig(ao);
            float gc = fmaf(fg, cst, ig * gt);
            float df = cst - gc;
            float dtv = dt_time[row0 + s];
            cst = fmaf(df, __expf(-dl * dtv), gc);
            float hn = og * tanhf(cst);
            float4 stv;
            stv.x = 2.f * gc; stv.y = 2.f * df; stv.z = dl * dtv; stv.w = av * og;
            Gst4[(size_t)(row0 + s) * 512 + e * 128 + l] = stv;
            float hi = __shfl_down(hn, 1, 64);
            if ((l & 1) == 0) {
                unsigned pw = pack2h(hn, hi);
                hOut[s * 64 + (l >> 1)] = pw;
                const int wi = (e * 64 + (l >> 1)) * 2 + s;
                unsigned* basep = hbuf + (size_t)(((t + 1) & 1) * 64 + grp) * 4 * 512;
                #pragma unroll
                for (int c = 0; c < 4; ++c) {
                    if (c != e) {
                        __hip_atomic_store(basep + (size_t)c * 512 + wi, pw,
                                           __ATOMIC_RELAXED, __HIP_MEMORY_SCOPE_AGENT);
                    }
                }
            }
            float lm = av * hn;
            #pragma unroll
            for (int off = 32; off > 0; off >>= 1) lm += __shfl_down(lm, off, 64);
            if ((tid & 63) == 0) red[tid >> 6] = lm;
        }
        __syncthreads();   // bar4: hOut/red ready for next step + lam write
        if (tid == 0) {
            lam_out[(row0 + 0) * 4 + e] = red[0] + red[1];
            lam_out[(row0 + 1) * 4 + e] = red[2] + red[3];
        }
    }
}

// ---------------- K3: trapezoid; grid 16384 = (row, e), 256 thr, half-split ----------------
// tuple = e*128 + (tid&127); tid<128 -> k=0..48 (12 chain iters), tid>=128 -> k=49..100 (13).
__global__ __launch_bounds__(256) void k3_trap(
    const float4* __restrict__ Gst4, const float* __restrict__ dt_time,
    float* __restrict__ integ_out)
{
    __shared__ float red[4];
    const int bidx = blockIdx.x;
    const int row = bidx >> 2;
    const int e   = bidx & 3;
    const int tid = threadIdx.x;
    const int l   = tid & 127;
    const int half = tid >> 7;
    const float dtv = dt_time[row];
    float4 stv = Gst4[(size_t)row * 512 + e * 128 + l];
    float g2 = stv.x, d2 = stv.y, q = stv.z, ao = stv.w;
    float r  = __expf(-0.01f * q);
    float r2 = r * r, r4 = r2 * r2;
    float T;
    if (half == 0) {
        float E1 = r, E2 = r2, E3 = r2 * r, E4 = r4;
        float s1 = 0.f, s2 = 0.f, s3 = 0.f, s4 = 0.f;
        #pragma unroll
        for (int k = 0; k < 12; ++k) {      // k = 1..48
            s1 += sig_e(fmaf(d2, E1, g2)); E1 *= r4;
            s2 += sig_e(fmaf(d2, E2, g2)); E2 *= r4;
            s3 += sig_e(fmaf(d2, E3, g2)); E3 *= r4;
            s4 += sig_e(fmaf(d2, E4, g2)); E4 *= r4;
        }
        T = 48.5f - 2.f * ((s1 + s2) + (s3 + s4)) - sig_e(g2 + d2);
    } else {
        float E49 = __expf(-0.49f * q);
        float E1 = E49, E2 = E49 * r, E3 = E49 * r2, E4 = E49 * r2 * r;
        float s1 = 0.f, s2 = 0.f, s3 = 0.f, s4 = 0.f;
        #pragma unroll
        for (int k = 0; k < 13; ++k) {      // k = 49..100
            s1 += sig_e(fmaf(d2, E1, g2)); E1 *= r4;
            s2 += sig_e(fmaf(d2, E2, g2)); E2 *= r4;
            s3 += sig_e(fmaf(d2, E3, g2)); E3 *= r4;
            s4 += sig_e(fmaf(d2, E4, g2)); E4 *= r4;
        }
        float e100 = __expf(-q);
        T = 51.5f - 2.f * ((s1 + s2) + (s3 + s4)) + sig_e(fmaf(d2, e100, g2));
    }
    float v = ao * T;
    #pragma unroll
    for (int off = 32; off > 0; off >>= 1) v += __shfl_down(v, off, 64);
    if ((tid & 63) == 0) red[tid >> 6] = v;
    __syncthreads();
    if (tid == 0) {
        float vv = (red[0] + red[1]) + (red[2] + red[3]);
        integ_out[row * 4 + e] = vv * (dtv * 0.01f);
    }
}

extern "C" void kernel_launch(void* const* d_in, const int* in_sizes, int n_in,
                              void* d_out, int out_size, void* d_ws, size_t ws_size,
                              hipStream_t stream)
{
    const float* x_time  = (const float*)d_in[0];
    const float* dt_time = (const float*)d_in[1];
    const float* Wh_w = (const float*)d_in[2];
    const float* Wh_b = (const float*)d_in[3];
    const float* Wi_w = (const float*)d_in[4];
    const float* Wi_b = (const float*)d_in[5];
    const float* Wf_w = (const float*)d_in[6];
    const float* Wf_b = (const float*)d_in[7];
    const float* Wd_w = (const float*)d_in[8];
    const float* Wd_b = (const float*)d_in[9];
    const float* Wg_w = (const float*)d_in[10];
    const float* Wg_b = (const float*)d_in[11];
    const float* Wo_w = (const float*)d_in[12];
    const float* Wo_b = (const float*)d_in[13];
    const float* alpha = (const float*)d_in[14];

    float* ws = (float*)d_ws;
    float* XG   = ws + OFF_XG;
    float4* Gst4 = (float4*)(ws + OFF_GST);
    unsigned* hbuf = (unsigned*)(ws + OFF_HBUF);
    float* lam_out   = (float*)d_out;
    float* integ_out = lam_out + 32 * 128 * 4;

    k0_pack<<<1920, 256, 0, stream>>>(Wh_w, Wh_b, Wi_w, Wi_b, Wf_w, Wf_b,
                                      Wd_w, Wd_b, Wg_w, Wg_b, Wo_w, Wo_b, ws);
    k1_xproj<<<3072, 256, 0, stream>>>(x_time, ws, XG);
    k2_recur<<<256, 512, 0, stream>>>(
        (const uint4*)(ws + OFF_WHHH), (const unsigned*)(ws + OFF_WGH),
        XG, dt_time, alpha, Gst4, hbuf, lam_out);
    k3_trap<<<16384, 256, 0, stream>>>(Gst4, dt_time, integ_out);
}